// Round 5
// baseline (834.190 us; speedup 1.0000x reference)
//
#include <hip/hip_runtime.h>

#define NEG 0.2f
#define SCHUNK 1024
typedef unsigned short u16;

__device__ __forceinline__ float sigmoidf_(float v){ return 1.f/(1.f+__expf(-v)); }
__device__ __forceinline__ int rfl_(int v){ return __builtin_amdgcn_readfirstlane(v); }
__device__ __forceinline__ float bf2f_(u16 u){ return __uint_as_float(((unsigned)u)<<16); }
__device__ __forceinline__ u16 f2bf_(float f){
  unsigned u = __float_as_uint(f);
  u += 0x7FFFu + ((u>>16)&1u);
  return (u16)(u>>16);
}
// 16-lane (head-group) sum via DPP row rotations: pure VALU, no DS pipe.
template<int C>
__device__ __forceinline__ float dppadd_(float p){
  int r = __builtin_amdgcn_update_dpp(0, __float_as_int(p), C, 0xF, 0xF, true);
  return p + __int_as_float(r);
}
__device__ __forceinline__ float dppsum16_(float p){
  p = dppadd_<0x121>(p);  // row_ror:1
  p = dppadd_<0x122>(p);  // row_ror:2
  p = dppadd_<0x124>(p);  // row_ror:4
  p = dppadd_<0x128>(p);  // row_ror:8
  return p;
}

// ---------------- encoder: h = relu([x,pos,temb[nt]] @ W1 + b1) @ W2 + b2 ----------------
// weights held per-lane in VGPRs; node-dim broadcast via per-wave LDS transpose tile
__global__ __launch_bounds__(256) void enc_kernel(
    const float* __restrict__ x, const float* __restrict__ pos,
    const int* __restrict__ ntype, const float* __restrict__ temb,
    const float* __restrict__ W1, const float* __restrict__ b1,
    const float* __restrict__ W2, const float* __restrict__ b2,
    float* __restrict__ hout, int N)
{
  __shared__ float fT[4][256];
  __shared__ float tT[4][256];
  int lane = threadIdx.x & 63;
  int wid  = threadIdx.x >> 6;
  int n0 = (blockIdx.x*4 + wid)*4;
  if (n0 >= N) return;
  float w1[18], w2[64];
  #pragma unroll
  for (int k=0;k<18;k++) w1[k]=W1[k*64+lane];
  #pragma unroll
  for (int k=0;k<64;k++) w2[k]=W2[k*64+lane];
  float b1v=b1[lane], b2v=b2[lane];
  float f[4];
  #pragma unroll
  for (int m=0;m<4;m++){
    int n=n0+m; f[m]=0.f;
    if (n<N){
      if (lane<7)       f[m]=x[(size_t)n*7+lane];
      else if (lane<10) f[m]=pos[(size_t)n*3+lane-7];
      else if (lane<18) f[m]=temb[ntype[n]*8+lane-10];
    }
  }
  *(float4*)&fT[wid][lane*4] = make_float4(f[0],f[1],f[2],f[3]);
  float t[4];
  #pragma unroll
  for (int m=0;m<4;m++) t[m]=b1v;
  #pragma unroll
  for (int k=0;k<18;k++){
    float4 fb = *(const float4*)&fT[wid][k*4];
    t[0]+=fb.x*w1[k]; t[1]+=fb.y*w1[k]; t[2]+=fb.z*w1[k]; t[3]+=fb.w*w1[k];
  }
  #pragma unroll
  for (int m=0;m<4;m++) t[m]=fmaxf(t[m],0.f);
  *(float4*)&tT[wid][lane*4] = make_float4(t[0],t[1],t[2],t[3]);
  float o[4];
  #pragma unroll
  for (int m=0;m<4;m++) o[m]=b2v;
  #pragma unroll
  for (int k=0;k<64;k++){
    float4 tb = *(const float4*)&tT[wid][k*4];
    o[0]+=tb.x*w2[k]; o[1]+=tb.y*w2[k]; o[2]+=tb.z*w2[k]; o[3]+=tb.w*w2[k];
  }
  #pragma unroll
  for (int m=0;m<4;m++){ int n=n0+m; if (n<N) hout[(size_t)n*64+lane]=o[m]; }
}

// ---------------- degree ----------------
__global__ void deg_kernel(const int* __restrict__ ei, int* __restrict__ deg, int E)
{
  int e = blockIdx.x*256 + threadIdx.x;
  if (e>=E) return;
  atomicAdd(deg + ei[E+e], 1);
}

// ---------------- 3-phase multi-block exclusive scan of (deg+1) -> offs[N] ----------------
__global__ __launch_bounds__(256) void scan_reduce(const int* __restrict__ deg, int* __restrict__ bsum, int N)
{
  int base = blockIdx.x*SCHUNK + threadIdx.x*4;
  int s=0;
  #pragma unroll
  for (int j=0;j<4;j++){ int i=base+j; s += (i<N)? deg[i]+1 : 0; }
  #pragma unroll
  for (int d=1;d<64;d<<=1) s += __shfl_xor(s,d);
  __shared__ int ws[4];
  if ((threadIdx.x&63)==0) ws[threadIdx.x>>6]=s;
  __syncthreads();
  if (threadIdx.x==0) bsum[blockIdx.x]=ws[0]+ws[1]+ws[2]+ws[3];
}

__global__ __launch_bounds__(1024) void scan_bsums(const int* __restrict__ bsum, int* __restrict__ bscan, int NB)
{
  int tid = threadIdx.x;
  int lane = tid&63, w = tid>>6;
  int v = (tid<NB)? bsum[tid] : 0;
  int inc = v;
  #pragma unroll
  for (int d=1;d<64;d<<=1){ int t=__shfl_up(inc,d); if (lane>=d) inc+=t; }
  __shared__ int wsum[16], woff[16];
  if (lane==63) wsum[w]=inc;
  __syncthreads();
  if (w==0){
    int s=(lane<16)?wsum[lane]:0; int sc=s;
    #pragma unroll
    for (int d=1;d<16;d<<=1){ int t=__shfl_up(sc,d); if (lane>=d) sc+=t; }
    if (lane<16) woff[lane]=sc-s;
  }
  __syncthreads();
  int excl = woff[w] + inc - v;
  if (tid<NB) bscan[tid]=excl;
}

__global__ __launch_bounds__(256) void scan_final(const int* __restrict__ deg, const int* __restrict__ bscan,
                                                  int* __restrict__ offs, int N)
{
  int lane = threadIdx.x&63, w = threadIdx.x>>6;
  int base = blockIdx.x*SCHUNK + threadIdx.x*4;
  int v[4]; int s=0;
  #pragma unroll
  for (int j=0;j<4;j++){ int i=base+j; v[j]=(i<N)?deg[i]+1:0; s+=v[j]; }
  int inc=s;
  #pragma unroll
  for (int d=1;d<64;d<<=1){ int t=__shfl_up(inc,d); if (lane>=d) inc+=t; }
  __shared__ int wsum[4], woff[4];
  if (lane==63) wsum[w]=inc;
  __syncthreads();
  if (threadIdx.x==0){ woff[0]=0; woff[1]=wsum[0]; woff[2]=wsum[0]+wsum[1]; woff[3]=wsum[0]+wsum[1]+wsum[2]; }
  __syncthreads();
  int excl = bscan[blockIdx.x] + woff[w] + (inc - s);
  #pragma unroll
  for (int j=0;j<4;j++){ int i=base+j; if (i<N) offs[i]=excl; excl+=v[j]; }
}

// ---------------- CSR fill: csr2[slot] = {edge_id, src}; self-loop handled in gat ----------------
__global__ void fill_kernel(const int* __restrict__ ei, const int* __restrict__ offs,
                            int* __restrict__ cursor, int2* __restrict__ csr2, int E)
{
  int e = blockIdx.x*256 + threadIdx.x;
  if (e >= E) return;
  int dst = ei[E + e];
  int p = atomicAdd(cursor + dst, 1);
  csr2[offs[dst] + p] = make_int2(e, ei[e]);
}

// ---------------- xl = h@Wl+bl, xr = h@Wr+br -> bf16 outputs ----------------
// weight columns in VGPRs (128 regs); node broadcast via per-wave LDS transpose tile
__global__ __launch_bounds__(256) void xfrm_kernel(
    const float* __restrict__ hin,
    const float* __restrict__ Wl, const float* __restrict__ bl,
    const float* __restrict__ Wr, const float* __restrict__ br,
    u16* __restrict__ xlo, u16* __restrict__ xro, int N)
{
  __shared__ float hT[4][256];
  int lane=threadIdx.x&63;
  int wid=threadIdx.x>>6;
  int n0=(blockIdx.x*4+wid)*4;
  if (n0>=N) return;
  float hv[4];
  #pragma unroll
  for (int m=0;m<4;m++){ int n=n0+m; hv[m]=(n<N)? hin[(size_t)n*64+lane]:0.f; }
  *(float4*)&hT[wid][lane*4] = make_float4(hv[0],hv[1],hv[2],hv[3]);
  float wl[64], wr[64];
  #pragma unroll
  for (int k=0;k<64;k++){ wl[k]=Wl[k*64+lane]; wr[k]=Wr[k*64+lane]; }
  float blv=bl[lane], brv=br[lane];
  float al[4], ar[4];
  #pragma unroll
  for (int m=0;m<4;m++){ al[m]=blv; ar[m]=brv; }
  #pragma unroll
  for (int k=0;k<64;k++){
    float4 hb = *(const float4*)&hT[wid][k*4];   // uniform addr -> broadcast
    al[0]+=hb.x*wl[k]; al[1]+=hb.y*wl[k]; al[2]+=hb.z*wl[k]; al[3]+=hb.w*wl[k];
    ar[0]+=hb.x*wr[k]; ar[1]+=hb.y*wr[k]; ar[2]+=hb.z*wr[k]; ar[3]+=hb.w*wr[k];
  }
  #pragma unroll
  for (int m=0;m<4;m++){
    int n=n0+m;
    if (n<N){ xlo[(size_t)n*64+lane]=f2bf_(al[m]); xro[(size_t)n*64+lane]=f2bf_(ar[m]); }
  }
}

// ---------------- fused GATv2 layer: wave per dst node ----------------
// bf16 xl/xr gathers, scalarized edge metadata, DPP 16-lane reduce, defer-max
// online softmax. Self-loop's ea@We term = (sum of per-edge d terms)/deg (linear).
#define EDGE_STEP(EIDX, EADD, XV) do {                                       \
    float s_ = (XV) + xrv + (EADD);                                          \
    s_ = fmaxf(s_, NEG*s_);                                                  \
    float p_ = dppsum16_(s_*attv);                                           \
    if (isbase) aout[(size_t)(EIDX)*4+h] = p_;                               \
    if (__all(p_ <= mmax)) {                                                 \
      float w_ = __expf(p_ - mmax);                                          \
      ssum += w_; acc += w_*(XV);                                            \
    } else {                                                                 \
      float mn_ = fmaxf(mmax, p_);                                           \
      float sc_ = __expf(mmax - mn_);                                        \
      float w_  = __expf(p_ - mn_);                                          \
      ssum = ssum*sc_ + w_;                                                  \
      acc  = acc*sc_ + w_*(XV);                                              \
      mmax = mn_;                                                            \
    }                                                                        \
  } while(0)

#define EDGE_PRE(J) \
    int e##J = rfl_(c##J.x), s##J = rfl_(c##J.y); \
    const float2* q##J = (const float2*)(eattr + (size_t)e##J*6); \
    float2 A##J=q##J[0], B##J=q##J[1], C##J=q##J[2]; \
    float xv##J = bf2f_(xlb[(size_t)s##J*64+lane]);

#define EDGE_BODY(J) \
    float d##J = A##J.x*we0 + A##J.y*we1 + B##J.x*we2 + B##J.y*we3 + C##J.x*we4 + C##J.y*we5; \
    dsum += d##J; \
    EDGE_STEP(e##J, d##J, xv##J);

__global__ __launch_bounds__(256) void gat_kernel(
    const int2* __restrict__ csr2, const int* __restrict__ offs, const int* __restrict__ deg,
    const float* __restrict__ eattr,
    const u16* __restrict__ xlb, const u16* __restrict__ xrb,
    const float* __restrict__ We, const float* __restrict__ att,
    const float* __restrict__ bias,
    float* __restrict__ aout, float2* __restrict__ msbuf,
    float* __restrict__ hout,
    int E, int N, int do_relu)
{
  int lane = threadIdx.x & 63;
  int n = blockIdx.x*4 + (threadIdx.x>>6);
  if (n >= N) return;
  float we0=We[lane], we1=We[64+lane], we2=We[128+lane],
        we3=We[192+lane], we4=We[256+lane], we5=We[320+lane];
  float attv = att[lane];
  float bv = bias[lane];
  float xrv = bf2f_(xrb[(size_t)n*64+lane]);
  int h = lane >> 4;
  bool isbase = (lane & 15) == 0;
  int o0 = rfl_(offs[n]);
  int dg = rfl_(deg[n]);
  int oend = o0 + dg;
  float mmax = -3.402823e38f, ssum=0.f, acc=0.f, dsum=0.f;
  int o = o0;
  for (; o+4 <= oend; o += 4){
    int2 c0=csr2[o], c1=csr2[o+1], c2=csr2[o+2], c3=csr2[o+3];
    EDGE_PRE(0); EDGE_PRE(1); EDGE_PRE(2); EDGE_PRE(3);
    EDGE_BODY(0); EDGE_BODY(1); EDGE_BODY(2); EDGE_BODY(3);
  }
  for (; o < oend; ++o){
    int2 c0=csr2[o];
    EDGE_PRE(0);
    EDGE_BODY(0);
  }
  // self-loop (edge id E+n): ea@We term = mean of per-edge d terms (linearity)
  {
    float dS = dsum * (1.f/fmaxf((float)dg,1.f));
    float xvS = bf2f_(xlb[(size_t)n*64+lane]);
    EDGE_STEP(E+n, dS, xvS);
  }
  float sinv = 1.f/(ssum + 1e-16f);
  if (isbase) msbuf[(size_t)n*4+h] = make_float2(mmax, sinv);
  float outv = acc*sinv + bv;
  if (do_relu) outv = fmaxf(outv, 0.f);
  hout[(size_t)n*64+lane] = outv;
}

// ---------------- alpha finalize: one thread per edge, float4 I/O ----------------
__global__ void alpha_kernel(const int* __restrict__ ei, const float2* __restrict__ msbuf,
                             float4* __restrict__ aout4, int E, int N)
{
  int e = blockIdx.x*256 + threadIdx.x;
  if (e >= E+N) return;
  int dst = (e<E)? ei[E+e] : (e-E);
  float4 r = aout4[e];
  const float2* mp = msbuf + (size_t)dst*4;
  float2 m0=mp[0], m1=mp[1], m2=mp[2], m3=mp[3];
  float4 o;
  o.x = __expf(r.x - m0.x)*m0.y;
  o.y = __expf(r.y - m1.x)*m1.y;
  o.z = __expf(r.z - m2.x)*m2.y;
  o.w = __expf(r.w - m3.x)*m3.y;
  aout4[e] = o;
}

// ---------------- fused GRU + decoder: 4 nodes per wave ----------------
__global__ __launch_bounds__(256) void grudec_kernel(
    const float* __restrict__ h2, const float* __restrict__ hid,
    const float* __restrict__ Wi, const float* __restrict__ bi,
    const float* __restrict__ Wh, const float* __restrict__ bh,
    const int* __restrict__ Tptr,
    const float* __restrict__ W1, const float* __restrict__ b1,
    const float* __restrict__ W2, const float* __restrict__ b2,
    const float* __restrict__ x, const float* __restrict__ pos,
    float* __restrict__ nf, float* __restrict__ fout, int N)
{
  __shared__ float sW2[448];
  __shared__ float sb2[7];
  __shared__ float tT[4][256];
  __shared__ float pT[4][256];
  for (int i=threadIdx.x;i<448;i+=256) sW2[i]=W2[i];
  if (threadIdx.x<7)  sb2[threadIdx.x]=b2[threadIdx.x];
  __syncthreads();
  int lane = threadIdx.x & 63;
  int wid  = threadIdx.x >> 6;
  int n0 = (blockIdx.x*4 + wid)*4;
  int T = *Tptr;
  float hv[4], nfv[4];
  #pragma unroll
  for (int m=0;m<4;m++){ int n=n0+m; hv[m] = (n<N)? h2[(size_t)n*64+lane] : 0.f; }
  if (n0 < T){
    float pv[4];
    #pragma unroll
    for (int m=0;m<4;m++){ int n=n0+m; pv[m] = (n<T)? hid[(size_t)n*64+lane] : 0.f; }
    *(float4*)&tT[wid][lane*4] = make_float4(hv[0],hv[1],hv[2],hv[3]);
    *(float4*)&pT[wid][lane*4] = make_float4(pv[0],pv[1],pv[2],pv[3]);
    float gr[4],gz[4],gn[4],hr[4],hz[4],hn[4];
    #pragma unroll
    for (int m=0;m<4;m++){ gr[m]=0.f;gz[m]=0.f;gn[m]=0.f;hr[m]=0.f;hz[m]=0.f;hn[m]=0.f; }
    for (int k=0;k<64;k++){
      float4 hb = *(const float4*)&tT[wid][k*4];
      float4 pb = *(const float4*)&pT[wid][k*4];
      float wir=Wi[k*192+lane], wiz=Wi[k*192+64+lane], win=Wi[k*192+128+lane];
      float whr=Wh[k*192+lane], whz=Wh[k*192+64+lane], whn=Wh[k*192+128+lane];
      gr[0]+=hb.x*wir; gr[1]+=hb.y*wir; gr[2]+=hb.z*wir; gr[3]+=hb.w*wir;
      gz[0]+=hb.x*wiz; gz[1]+=hb.y*wiz; gz[2]+=hb.z*wiz; gz[3]+=hb.w*wiz;
      gn[0]+=hb.x*win; gn[1]+=hb.y*win; gn[2]+=hb.z*win; gn[3]+=hb.w*win;
      hr[0]+=pb.x*whr; hr[1]+=pb.y*whr; hr[2]+=pb.z*whr; hr[3]+=pb.w*whr;
      hz[0]+=pb.x*whz; hz[1]+=pb.y*whz; hz[2]+=pb.z*whz; hz[3]+=pb.w*whz;
      hn[0]+=pb.x*whn; hn[1]+=pb.y*whn; hn[2]+=pb.z*whn; hn[3]+=pb.w*whn;
    }
    float bir=bi[lane], biz=bi[64+lane], bin=bi[128+lane];
    float bhr=bh[lane], bhz=bh[64+lane], bhn=bh[128+lane];
    #pragma unroll
    for (int m=0;m<4;m++){
      int n=n0+m;
      if (n<T){
        float r  = sigmoidf_(gr[m]+bir + hr[m]+bhr);
        float z  = sigmoidf_(gz[m]+biz + hz[m]+bhz);
        float nn = tanhf(gn[m]+bin + r*(hn[m]+bhn));
        nfv[m] = (1.f-z)*nn + z*pv[m];
      } else {
        nfv[m] = hv[m];
      }
    }
  } else {
    #pragma unroll
    for (int m=0;m<4;m++) nfv[m] = hv[m];
  }
  #pragma unroll
  for (int m=0;m<4;m++){ int n=n0+m; if (n<N) nf[(size_t)n*64+lane]=nfv[m]; }
  // ---- decoder stage 1: t = relu(nf@W1 + b1) with W1 column in VGPRs ----
  float w1[64];
  #pragma unroll
  for (int k=0;k<64;k++) w1[k]=W1[k*64+lane];
  *(float4*)&tT[wid][lane*4] = make_float4(nfv[0],nfv[1],nfv[2],nfv[3]);
  float t[4];
  float b1v=b1[lane];
  #pragma unroll
  for (int m=0;m<4;m++) t[m]=b1v;
  #pragma unroll
  for (int k=0;k<64;k++){
    float4 nb = *(const float4*)&tT[wid][k*4];
    t[0]+=nb.x*w1[k]; t[1]+=nb.y*w1[k]; t[2]+=nb.z*w1[k]; t[3]+=nb.w*w1[k];
  }
  #pragma unroll
  for (int m=0;m<4;m++) t[m]=fmaxf(t[m],0.f);
  // ---- decoder stage 2: out = t@W2 + b2 (+ residuals) ----
  #pragma unroll
  for (int c=0;c<7;c++){
    float w = sW2[lane*7+c];
    float p0=t[0]*w, p1=t[1]*w, p2=t[2]*w, p3=t[3]*w;
    #pragma unroll
    for (int d=1;d<64;d<<=1){
      p0+=__shfl_xor(p0,d); p1+=__shfl_xor(p1,d); p2+=__shfl_xor(p2,d); p3+=__shfl_xor(p3,d);
    }
    if (lane==c){
      float b = sb2[c];
      float pm[4]={p0,p1,p2,p3};
      #pragma unroll
      for (int m=0;m<4;m++){
        int n=n0+m;
        if (n<N){
          float val = pm[m]+b;
          if (c<3)      val += pos[(size_t)n*3+c];
          else if (c<6) val += x[(size_t)n*7+(c-3)];
          fout[(size_t)n*7+c] = val;
        }
      }
    }
  }
}

extern "C" void kernel_launch(void* const* d_in, const int* in_sizes, int n_in,
                              void* d_out, int out_size, void* d_ws, size_t ws_size,
                              hipStream_t stream)
{
  const float* x     = (const float*)d_in[0];
  const float* pos   = (const float*)d_in[1];
  const int*   ntype = (const int*)d_in[2];
  const int*   eidx  = (const int*)d_in[3];
  const float* eattr = (const float*)d_in[4];
  const int*   Tptr  = (const int*)d_in[5];
  const float* hid   = (const float*)d_in[6];
  const float* temb  = (const float*)d_in[7];
  const float* encW1 = (const float*)d_in[8];
  const float* encb1 = (const float*)d_in[9];
  const float* encW2 = (const float*)d_in[10];
  const float* encb2 = (const float*)d_in[11];
  const float* gruWi = (const float*)d_in[12];
  const float* grubi = (const float*)d_in[13];
  const float* gruWh = (const float*)d_in[14];
  const float* grubh = (const float*)d_in[15];
  const float* decW1 = (const float*)d_in[16];
  const float* decb1 = (const float*)d_in[17];
  const float* decW2 = (const float*)d_in[18];
  const float* decb2 = (const float*)d_in[19];
  const float* gWl[2]  = {(const float*)d_in[20], (const float*)d_in[27]};
  const float* gbl[2]  = {(const float*)d_in[21], (const float*)d_in[28]};
  const float* gWr[2]  = {(const float*)d_in[22], (const float*)d_in[29]};
  const float* gbr[2]  = {(const float*)d_in[23], (const float*)d_in[30]};
  const float* gWe[2]  = {(const float*)d_in[24], (const float*)d_in[31]};
  const float* gatt[2] = {(const float*)d_in[25], (const float*)d_in[32]};
  const float* gbias[2]= {(const float*)d_in[26], (const float*)d_in[33]};

  int N  = in_sizes[0] / 7;
  int E  = in_sizes[3] / 2;
  int Ea = E + N;
  int NB = (N + SCHUNK - 1) / SCHUNK;

  char* w = (char*)d_ws;
  float* A      = (float*)w; w += (size_t)N*64*sizeof(float);
  float* B      = (float*)w; w += (size_t)N*64*sizeof(float);
  u16*   XL     = (u16*)w;  w += (size_t)N*64*sizeof(u16);
  u16*   XR     = (u16*)w;  w += (size_t)N*64*sizeof(u16);
  int*   deg    = (int*)w;   w += (size_t)N*sizeof(int);
  int*   cursor = (int*)w;   w += (size_t)N*sizeof(int);
  int*   offs   = (int*)w;   w += (size_t)N*sizeof(int);
  int*   bsum   = (int*)w;   w += (size_t)NB*sizeof(int);
  int*   bscan  = (int*)w;   w += (size_t)NB*sizeof(int);
  float2* msbuf = (float2*)w; w += (size_t)N*4*sizeof(float2);
  int2*  csr2   = (int2*)w;  w += (size_t)Ea*sizeof(int2);

  float* out_final = (float*)d_out;
  float* out_nf    = out_final + (size_t)N*7;
  float* out_a1    = out_nf + (size_t)N*64;
  float* out_a2    = out_a1 + (size_t)Ea*4;

  hipMemsetAsync(deg, 0, (size_t)2*N*sizeof(int), stream);  // deg + cursor

  enc_kernel<<<(N+15)/16, 256, 0, stream>>>(x,pos,ntype,temb,encW1,encb1,encW2,encb2,A,N);
  deg_kernel<<<(E+255)/256, 256, 0, stream>>>(eidx, deg, E);
  scan_reduce<<<NB, 256, 0, stream>>>(deg, bsum, N);
  scan_bsums<<<1, 1024, 0, stream>>>(bsum, bscan, NB);
  scan_final<<<NB, 256, 0, stream>>>(deg, bscan, offs, N);
  fill_kernel<<<(E+255)/256, 256, 0, stream>>>(eidx, offs, cursor, csr2, E);

  // layer 1: h(A) -> XL,XR (bf16); out h1 -> B (relu)
  xfrm_kernel<<<(N+15)/16, 256, 0, stream>>>(A, gWl[0], gbl[0], gWr[0], gbr[0], XL, XR, N);
  gat_kernel<<<(N+3)/4, 256, 0, stream>>>(csr2, offs, deg, eattr, XL, XR,
      gWe[0], gatt[0], gbias[0], out_a1, msbuf, B, E, N, 1);
  alpha_kernel<<<(Ea+255)/256, 256, 0, stream>>>(eidx, msbuf, (float4*)out_a1, E, N);

  // layer 2: h1(B) -> XL,XR; out h2 -> A (no relu)
  xfrm_kernel<<<(N+15)/16, 256, 0, stream>>>(B, gWl[1], gbl[1], gWr[1], gbr[1], XL, XR, N);
  gat_kernel<<<(N+3)/4, 256, 0, stream>>>(csr2, offs, deg, eattr, XL, XR,
      gWe[1], gatt[1], gbias[1], out_a2, msbuf, A, E, N, 0);
  alpha_kernel<<<(Ea+255)/256, 256, 0, stream>>>(eidx, msbuf, (float4*)out_a2, E, N);

  grudec_kernel<<<(N+15)/16, 256, 0, stream>>>(A, hid, gruWi, grubi, gruWh, grubh, Tptr,
      decW1, decb1, decW2, decb2, x, pos, out_nf, out_final, N);
}

// Round 6
// 594.939 us; speedup vs baseline: 1.4021x; 1.4021x over previous
//
#include <hip/hip_runtime.h>

#define NEG 0.2f
#define SCHUNK 1024
typedef unsigned short u16;

__device__ __forceinline__ float sigmoidf_(float v){ return 1.f/(1.f+__expf(-v)); }
__device__ __forceinline__ int rfl_(int v){ return __builtin_amdgcn_readfirstlane(v); }
__device__ __forceinline__ float bf2f_(u16 u){ return __uint_as_float(((unsigned)u)<<16); }
__device__ __forceinline__ u16 f2bf_(float f){
  unsigned u = __float_as_uint(f);
  u += 0x7FFFu + ((u>>16)&1u);
  return (u16)(u>>16);
}
// 16-lane (head-group) sum via DPP row rotations: pure VALU, no DS pipe.
template<int C>
__device__ __forceinline__ float dppadd_(float p){
  int r = __builtin_amdgcn_update_dpp(0, __float_as_int(p), C, 0xF, 0xF, true);
  return p + __int_as_float(r);
}
__device__ __forceinline__ float dppsum16_(float p){
  p = dppadd_<0x121>(p);  // row_ror:1
  p = dppadd_<0x122>(p);  // row_ror:2
  p = dppadd_<0x124>(p);  // row_ror:4
  p = dppadd_<0x128>(p);  // row_ror:8
  return p;
}

// ---------------- encoder: h = relu([x,pos,temb[nt]] @ W1 + b1) @ W2 + b2 ----------------
// weights in LDS; activations via per-wave m-major transpose tiles (uniform reads)
__global__ __launch_bounds__(256) void enc_kernel(
    const float* __restrict__ x, const float* __restrict__ pos,
    const int* __restrict__ ntype, const float* __restrict__ temb,
    const float* __restrict__ W1, const float* __restrict__ b1,
    const float* __restrict__ W2, const float* __restrict__ b2,
    float* __restrict__ hout, int N)
{
  __shared__ float sW1[18*64];
  __shared__ float sW2[4096];
  __shared__ float fT[4][8*20];
  __shared__ float tT[4][8*64];
  for (int i=threadIdx.x; i<18*64; i+=256) sW1[i]=W1[i];
  for (int i=threadIdx.x; i<4096; i+=256)  sW2[i]=W2[i];
  __syncthreads();
  int lane = threadIdx.x & 63;
  int wid  = threadIdx.x >> 6;
  int n0 = (blockIdx.x*4 + wid)*8;
  if (n0 >= N) return;
  float b1v=b1[lane], b2v=b2[lane];
  #pragma unroll
  for (int m=0;m<8;m++){
    int n=n0+m; float fv=0.f;
    if (n<N){
      if (lane<7)       fv=x[(size_t)n*7+lane];
      else if (lane<10) fv=pos[(size_t)n*3+lane-7];
      else if (lane<18) fv=temb[ntype[n]*8+lane-10];
    }
    if (lane<20) fT[wid][m*20+lane]=fv;
  }
  float t[8];
  #pragma unroll
  for (int m=0;m<8;m++) t[m]=b1v;
  #pragma unroll 2
  for (int k=0;k<18;k++){
    float w=sW1[k*64+lane];
    #pragma unroll
    for (int m=0;m<8;m++) t[m] += fT[wid][m*20+k]*w;
  }
  #pragma unroll
  for (int m=0;m<8;m++){ t[m]=fmaxf(t[m],0.f); tT[wid][m*64+lane]=t[m]; }
  float o[8];
  #pragma unroll
  for (int m=0;m<8;m++) o[m]=b2v;
  #pragma unroll 2
  for (int k=0;k<64;k++){
    float w=sW2[k*64+lane];
    #pragma unroll
    for (int m=0;m<8;m++) o[m] += tT[wid][m*64+k]*w;
  }
  #pragma unroll
  for (int m=0;m<8;m++){ int n=n0+m; if (n<N) hout[(size_t)n*64+lane]=o[m]; }
}

// ---------------- degree ----------------
__global__ void deg_kernel(const int* __restrict__ ei, int* __restrict__ deg, int E)
{
  int e = blockIdx.x*256 + threadIdx.x;
  if (e>=E) return;
  atomicAdd(deg + ei[E+e], 1);
}

// ---------------- 3-phase multi-block exclusive scan of (deg+1) -> offs[N] ----------------
__global__ __launch_bounds__(256) void scan_reduce(const int* __restrict__ deg, int* __restrict__ bsum, int N)
{
  int base = blockIdx.x*SCHUNK + threadIdx.x*4;
  int s=0;
  #pragma unroll
  for (int j=0;j<4;j++){ int i=base+j; s += (i<N)? deg[i]+1 : 0; }
  #pragma unroll
  for (int d=1;d<64;d<<=1) s += __shfl_xor(s,d);
  __shared__ int ws[4];
  if ((threadIdx.x&63)==0) ws[threadIdx.x>>6]=s;
  __syncthreads();
  if (threadIdx.x==0) bsum[blockIdx.x]=ws[0]+ws[1]+ws[2]+ws[3];
}

__global__ __launch_bounds__(1024) void scan_bsums(const int* __restrict__ bsum, int* __restrict__ bscan, int NB)
{
  int tid = threadIdx.x;
  int lane = tid&63, w = tid>>6;
  int v = (tid<NB)? bsum[tid] : 0;
  int inc = v;
  #pragma unroll
  for (int d=1;d<64;d<<=1){ int t=__shfl_up(inc,d); if (lane>=d) inc+=t; }
  __shared__ int wsum[16], woff[16];
  if (lane==63) wsum[w]=inc;
  __syncthreads();
  if (w==0){
    int s=(lane<16)?wsum[lane]:0; int sc=s;
    #pragma unroll
    for (int d=1;d<16;d<<=1){ int t=__shfl_up(sc,d); if (lane>=d) sc+=t; }
    if (lane<16) woff[lane]=sc-s;
  }
  __syncthreads();
  int excl = woff[w] + inc - v;
  if (tid<NB) bscan[tid]=excl;
}

__global__ __launch_bounds__(256) void scan_final(const int* __restrict__ deg, const int* __restrict__ bscan,
                                                  int* __restrict__ offs, int N)
{
  int lane = threadIdx.x&63, w = threadIdx.x>>6;
  int base = blockIdx.x*SCHUNK + threadIdx.x*4;
  int v[4]; int s=0;
  #pragma unroll
  for (int j=0;j<4;j++){ int i=base+j; v[j]=(i<N)?deg[i]+1:0; s+=v[j]; }
  int inc=s;
  #pragma unroll
  for (int d=1;d<64;d<<=1){ int t=__shfl_up(inc,d); if (lane>=d) inc+=t; }
  __shared__ int wsum[4], woff[4];
  if (lane==63) wsum[w]=inc;
  __syncthreads();
  if (threadIdx.x==0){ woff[0]=0; woff[1]=wsum[0]; woff[2]=wsum[0]+wsum[1]; woff[3]=wsum[0]+wsum[1]+wsum[2]; }
  __syncthreads();
  int excl = bscan[blockIdx.x] + woff[w] + (inc - s);
  #pragma unroll
  for (int j=0;j<4;j++){ int i=base+j; if (i<N) offs[i]=excl; excl+=v[j]; }
}

// ---------------- CSR fill: csr2[slot] = {edge_id, src}; self-loop handled in gat ----------------
__global__ void fill_kernel(const int* __restrict__ ei, const int* __restrict__ offs,
                            int* __restrict__ cursor, int2* __restrict__ csr2, int E)
{
  int e = blockIdx.x*256 + threadIdx.x;
  if (e >= E) return;
  int dst = ei[E + e];
  int p = atomicAdd(cursor + dst, 1);
  csr2[offs[dst] + p] = make_int2(e, ei[e]);
}

// ---------------- xl = h@Wl+bl, xr = h@Wr+br -> bf16 outputs ----------------
// weights in LDS (32KB); per-wave m-major transpose tile (16 nodes/wave)
__global__ __launch_bounds__(256) void xfrm_kernel(
    const float* __restrict__ hin,
    const float* __restrict__ Wl, const float* __restrict__ bl,
    const float* __restrict__ Wr, const float* __restrict__ br,
    u16* __restrict__ xlo, u16* __restrict__ xro, int N)
{
  __shared__ float sWl[4096], sWr[4096];
  __shared__ float hT[4][16*64];
  for (int i=threadIdx.x;i<4096;i+=256){ sWl[i]=Wl[i]; sWr[i]=Wr[i]; }
  __syncthreads();
  int lane=threadIdx.x&63;
  int wid=threadIdx.x>>6;
  int n0=(blockIdx.x*4+wid)*16;
  if (n0>=N) return;
  #pragma unroll
  for (int m=0;m<16;m++){
    int n=n0+m;
    hT[wid][m*64+lane] = (n<N)? hin[(size_t)n*64+lane] : 0.f;
  }
  float blv=bl[lane], brv=br[lane];
  float al[16], ar[16];
  #pragma unroll
  for (int m=0;m<16;m++){ al[m]=blv; ar[m]=brv; }
  #pragma unroll 2
  for (int k=0;k<64;k++){
    float wl=sWl[k*64+lane], wr=sWr[k*64+lane];
    #pragma unroll
    for (int m=0;m<16;m++){
      float hb = hT[wid][m*64+k];   // wave-uniform -> broadcast, ds_read2-merged
      al[m]+=hb*wl; ar[m]+=hb*wr;
    }
  }
  #pragma unroll
  for (int m=0;m<16;m++){
    int n=n0+m;
    if (n<N){ xlo[(size_t)n*64+lane]=f2bf_(al[m]); xro[(size_t)n*64+lane]=f2bf_(ar[m]); }
  }
}

// ---------------- fused GATv2 layer: wave per dst node ----------------
// bf16 xl/xr gathers, scalarized edge metadata, DPP 16-lane reduce, defer-max
// online softmax. Self-loop's ea@We term = (sum of per-edge d terms)/deg (linear).
#define EDGE_STEP(EIDX, EADD, XV) do {                                       \
    float s_ = (XV) + xrv + (EADD);                                          \
    s_ = fmaxf(s_, NEG*s_);                                                  \
    float p_ = dppsum16_(s_*attv);                                           \
    if (isbase) aout[(size_t)(EIDX)*4+h] = p_;                               \
    if (__all(p_ <= mmax)) {                                                 \
      float w_ = __expf(p_ - mmax);                                          \
      ssum += w_; acc += w_*(XV);                                            \
    } else {                                                                 \
      float mn_ = fmaxf(mmax, p_);                                           \
      float sc_ = __expf(mmax - mn_);                                        \
      float w_  = __expf(p_ - mn_);                                          \
      ssum = ssum*sc_ + w_;                                                  \
      acc  = acc*sc_ + w_*(XV);                                              \
      mmax = mn_;                                                            \
    }                                                                        \
  } while(0)

#define EDGE_PRE(J) \
    int e##J = rfl_(c##J.x), s##J = rfl_(c##J.y); \
    const float2* q##J = (const float2*)(eattr + (size_t)e##J*6); \
    float2 A##J=q##J[0], B##J=q##J[1], C##J=q##J[2]; \
    float xv##J = bf2f_(xlb[(size_t)s##J*64+lane]);

#define EDGE_BODY(J) \
    float d##J = A##J.x*we0 + A##J.y*we1 + B##J.x*we2 + B##J.y*we3 + C##J.x*we4 + C##J.y*we5; \
    dsum += d##J; \
    EDGE_STEP(e##J, d##J, xv##J);

__global__ __launch_bounds__(256) void gat_kernel(
    const int2* __restrict__ csr2, const int* __restrict__ offs, const int* __restrict__ deg,
    const float* __restrict__ eattr,
    const u16* __restrict__ xlb, const u16* __restrict__ xrb,
    const float* __restrict__ We, const float* __restrict__ att,
    const float* __restrict__ bias,
    float* __restrict__ aout, float2* __restrict__ msbuf,
    float* __restrict__ hout,
    int E, int N, int do_relu)
{
  int lane = threadIdx.x & 63;
  int n = blockIdx.x*4 + (threadIdx.x>>6);
  if (n >= N) return;
  float we0=We[lane], we1=We[64+lane], we2=We[128+lane],
        we3=We[192+lane], we4=We[256+lane], we5=We[320+lane];
  float attv = att[lane];
  float bv = bias[lane];
  float xrv = bf2f_(xrb[(size_t)n*64+lane]);
  int h = lane >> 4;
  bool isbase = (lane & 15) == 0;
  int o0 = rfl_(offs[n]);
  int dg = rfl_(deg[n]);
  int oend = o0 + dg;
  float mmax = -3.402823e38f, ssum=0.f, acc=0.f, dsum=0.f;
  int o = o0;
  for (; o+4 <= oend; o += 4){
    int2 c0=csr2[o], c1=csr2[o+1], c2=csr2[o+2], c3=csr2[o+3];
    EDGE_PRE(0); EDGE_PRE(1); EDGE_PRE(2); EDGE_PRE(3);
    EDGE_BODY(0); EDGE_BODY(1); EDGE_BODY(2); EDGE_BODY(3);
  }
  for (; o < oend; ++o){
    int2 c0=csr2[o];
    EDGE_PRE(0);
    EDGE_BODY(0);
  }
  // self-loop (edge id E+n): ea@We term = mean of per-edge d terms (linearity)
  {
    float dS = dsum * (1.f/fmaxf((float)dg,1.f));
    float xvS = bf2f_(xlb[(size_t)n*64+lane]);
    EDGE_STEP(E+n, dS, xvS);
  }
  float sinv = 1.f/(ssum + 1e-16f);
  if (isbase) msbuf[(size_t)n*4+h] = make_float2(mmax, sinv);
  float outv = acc*sinv + bv;
  if (do_relu) outv = fmaxf(outv, 0.f);
  hout[(size_t)n*64+lane] = outv;
}

// ---------------- alpha finalize: one thread per edge, float4 I/O ----------------
__global__ void alpha_kernel(const int* __restrict__ ei, const float2* __restrict__ msbuf,
                             float4* __restrict__ aout4, int E, int N)
{
  int e = blockIdx.x*256 + threadIdx.x;
  if (e >= E+N) return;
  int dst = (e<E)? ei[E+e] : (e-E);
  float4 r = aout4[e];
  const float2* mp = msbuf + (size_t)dst*4;
  float2 m0=mp[0], m1=mp[1], m2=mp[2], m3=mp[3];
  float4 o;
  o.x = __expf(r.x - m0.x)*m0.y;
  o.y = __expf(r.y - m1.x)*m1.y;
  o.z = __expf(r.z - m2.x)*m2.y;
  o.w = __expf(r.w - m3.x)*m3.y;
  aout4[e] = o;
}

// ---------------- fused GRU + decoder: 8 nodes per wave, W1 in LDS ----------------
__global__ __launch_bounds__(256) void grudec_kernel(
    const float* __restrict__ h2, const float* __restrict__ hid,
    const float* __restrict__ Wi, const float* __restrict__ bi,
    const float* __restrict__ Wh, const float* __restrict__ bh,
    const int* __restrict__ Tptr,
    const float* __restrict__ W1, const float* __restrict__ b1,
    const float* __restrict__ W2, const float* __restrict__ b2,
    const float* __restrict__ x, const float* __restrict__ pos,
    float* __restrict__ nf, float* __restrict__ fout, int N)
{
  __shared__ float sW1[4096];
  __shared__ float sW2[448];
  __shared__ float sb2[7];
  __shared__ float tT[4][8*64];
  __shared__ float pT[4][8*64];
  for (int i=threadIdx.x;i<4096;i+=256) sW1[i]=W1[i];
  for (int i=threadIdx.x;i<448;i+=256) sW2[i]=W2[i];
  if (threadIdx.x<7)  sb2[threadIdx.x]=b2[threadIdx.x];
  __syncthreads();
  int lane = threadIdx.x & 63;
  int wid  = threadIdx.x >> 6;
  int n0 = (blockIdx.x*4 + wid)*8;
  if (n0 >= N) return;
  int T = *Tptr;
  float hv[8], nfv[8];
  #pragma unroll
  for (int m=0;m<8;m++){ int n=n0+m; hv[m] = (n<N)? h2[(size_t)n*64+lane] : 0.f; }
  if (n0 < T){
    float pv[8];
    #pragma unroll
    for (int m=0;m<8;m++){ int n=n0+m; pv[m] = (n<T)? hid[(size_t)n*64+lane] : 0.f; }
    #pragma unroll
    for (int m=0;m<8;m++){ tT[wid][m*64+lane]=hv[m]; pT[wid][m*64+lane]=pv[m]; }
    float gr[8],gz[8],gn[8],hr[8],hz[8],hn[8];
    #pragma unroll
    for (int m=0;m<8;m++){ gr[m]=0.f;gz[m]=0.f;gn[m]=0.f;hr[m]=0.f;hz[m]=0.f;hn[m]=0.f; }
    for (int k=0;k<64;k++){
      float wir=Wi[k*192+lane], wiz=Wi[k*192+64+lane], win=Wi[k*192+128+lane];
      float whr=Wh[k*192+lane], whz=Wh[k*192+64+lane], whn=Wh[k*192+128+lane];
      #pragma unroll
      for (int m=0;m<8;m++){
        float a=tT[wid][m*64+k], b=pT[wid][m*64+k];
        gr[m]+=a*wir; gz[m]+=a*wiz; gn[m]+=a*win;
        hr[m]+=b*whr; hz[m]+=b*whz; hn[m]+=b*whn;
      }
    }
    float bir=bi[lane], biz=bi[64+lane], bin=bi[128+lane];
    float bhr=bh[lane], bhz=bh[64+lane], bhn=bh[128+lane];
    #pragma unroll
    for (int m=0;m<8;m++){
      int n=n0+m;
      if (n<T){
        float r  = sigmoidf_(gr[m]+bir + hr[m]+bhr);
        float z  = sigmoidf_(gz[m]+biz + hz[m]+bhz);
        float nn = tanhf(gn[m]+bin + r*(hn[m]+bhn));
        nfv[m] = (1.f-z)*nn + z*pv[m];
      } else {
        nfv[m] = hv[m];
      }
    }
  } else {
    #pragma unroll
    for (int m=0;m<8;m++) nfv[m] = hv[m];
  }
  #pragma unroll
  for (int m=0;m<8;m++){ int n=n0+m; if (n<N) nf[(size_t)n*64+lane]=nfv[m]; }
  // ---- decoder stage 1: t = relu(nf@W1 + b1), W1 in LDS ----
  #pragma unroll
  for (int m=0;m<8;m++) tT[wid][m*64+lane]=nfv[m];
  float t[8];
  float b1v=b1[lane];
  #pragma unroll
  for (int m=0;m<8;m++) t[m]=b1v;
  #pragma unroll 2
  for (int k=0;k<64;k++){
    float w=sW1[k*64+lane];
    #pragma unroll
    for (int m=0;m<8;m++) t[m] += tT[wid][m*64+k]*w;
  }
  #pragma unroll
  for (int m=0;m<8;m++) t[m]=fmaxf(t[m],0.f);
  // ---- decoder stage 2: out = t@W2 + b2 (+ residuals) ----
  #pragma unroll
  for (int c=0;c<7;c++){
    float w = sW2[lane*7+c];
    float p[8];
    #pragma unroll
    for (int m=0;m<8;m++) p[m]=t[m]*w;
    #pragma unroll
    for (int d=1;d<64;d<<=1){
      #pragma unroll
      for (int m=0;m<8;m++) p[m]+=__shfl_xor(p[m],d);
    }
    if (lane==c){
      float b = sb2[c];
      #pragma unroll
      for (int m=0;m<8;m++){
        int n=n0+m;
        if (n<N){
          float val = p[m]+b;
          if (c<3)      val += pos[(size_t)n*3+c];
          else if (c<6) val += x[(size_t)n*7+(c-3)];
          fout[(size_t)n*7+c] = val;
        }
      }
    }
  }
}

extern "C" void kernel_launch(void* const* d_in, const int* in_sizes, int n_in,
                              void* d_out, int out_size, void* d_ws, size_t ws_size,
                              hipStream_t stream)
{
  const float* x     = (const float*)d_in[0];
  const float* pos   = (const float*)d_in[1];
  const int*   ntype = (const int*)d_in[2];
  const int*   eidx  = (const int*)d_in[3];
  const float* eattr = (const float*)d_in[4];
  const int*   Tptr  = (const int*)d_in[5];
  const float* hid   = (const float*)d_in[6];
  const float* temb  = (const float*)d_in[7];
  const float* encW1 = (const float*)d_in[8];
  const float* encb1 = (const float*)d_in[9];
  const float* encW2 = (const float*)d_in[10];
  const float* encb2 = (const float*)d_in[11];
  const float* gruWi = (const float*)d_in[12];
  const float* grubi = (const float*)d_in[13];
  const float* gruWh = (const float*)d_in[14];
  const float* grubh = (const float*)d_in[15];
  const float* decW1 = (const float*)d_in[16];
  const float* decb1 = (const float*)d_in[17];
  const float* decW2 = (const float*)d_in[18];
  const float* decb2 = (const float*)d_in[19];
  const float* gWl[2]  = {(const float*)d_in[20], (const float*)d_in[27]};
  const float* gbl[2]  = {(const float*)d_in[21], (const float*)d_in[28]};
  const float* gWr[2]  = {(const float*)d_in[22], (const float*)d_in[29]};
  const float* gbr[2]  = {(const float*)d_in[23], (const float*)d_in[30]};
  const float* gWe[2]  = {(const float*)d_in[24], (const float*)d_in[31]};
  const float* gatt[2] = {(const float*)d_in[25], (const float*)d_in[32]};
  const float* gbias[2]= {(const float*)d_in[26], (const float*)d_in[33]};

  int N  = in_sizes[0] / 7;
  int E  = in_sizes[3] / 2;
  int Ea = E + N;
  int NB = (N + SCHUNK - 1) / SCHUNK;

  char* w = (char*)d_ws;
  float* A      = (float*)w; w += (size_t)N*64*sizeof(float);
  float* B      = (float*)w; w += (size_t)N*64*sizeof(float);
  u16*   XL     = (u16*)w;  w += (size_t)N*64*sizeof(u16);
  u16*   XR     = (u16*)w;  w += (size_t)N*64*sizeof(u16);
  int*   deg    = (int*)w;   w += (size_t)N*sizeof(int);
  int*   cursor = (int*)w;   w += (size_t)N*sizeof(int);
  int*   offs   = (int*)w;   w += (size_t)N*sizeof(int);
  int*   bsum   = (int*)w;   w += (size_t)NB*sizeof(int);
  int*   bscan  = (int*)w;   w += (size_t)NB*sizeof(int);
  float2* msbuf = (float2*)w; w += (size_t)N*4*sizeof(float2);
  int2*  csr2   = (int2*)w;  w += (size_t)Ea*sizeof(int2);

  float* out_final = (float*)d_out;
  float* out_nf    = out_final + (size_t)N*7;
  float* out_a1    = out_nf + (size_t)N*64;
  float* out_a2    = out_a1 + (size_t)Ea*4;

  hipMemsetAsync(deg, 0, (size_t)2*N*sizeof(int), stream);  // deg + cursor

  enc_kernel<<<(N+31)/32, 256, 0, stream>>>(x,pos,ntype,temb,encW1,encb1,encW2,encb2,A,N);
  deg_kernel<<<(E+255)/256, 256, 0, stream>>>(eidx, deg, E);
  scan_reduce<<<NB, 256, 0, stream>>>(deg, bsum, N);
  scan_bsums<<<1, 1024, 0, stream>>>(bsum, bscan, NB);
  scan_final<<<NB, 256, 0, stream>>>(deg, bscan, offs, N);
  fill_kernel<<<(E+255)/256, 256, 0, stream>>>(eidx, offs, cursor, csr2, E);

  // layer 1: h(A) -> XL,XR (bf16); out h1 -> B (relu)
  xfrm_kernel<<<(N+63)/64, 256, 0, stream>>>(A, gWl[0], gbl[0], gWr[0], gbr[0], XL, XR, N);
  gat_kernel<<<(N+3)/4, 256, 0, stream>>>(csr2, offs, deg, eattr, XL, XR,
      gWe[0], gatt[0], gbias[0], out_a1, msbuf, B, E, N, 1);
  alpha_kernel<<<(Ea+255)/256, 256, 0, stream>>>(eidx, msbuf, (float4*)out_a1, E, N);

  // layer 2: h1(B) -> XL,XR; out h2 -> A (no relu)
  xfrm_kernel<<<(N+63)/64, 256, 0, stream>>>(B, gWl[1], gbl[1], gWr[1], gbr[1], XL, XR, N);
  gat_kernel<<<(N+3)/4, 256, 0, stream>>>(csr2, offs, deg, eattr, XL, XR,
      gWe[1], gatt[1], gbias[1], out_a2, msbuf, A, E, N, 0);
  alpha_kernel<<<(Ea+255)/256, 256, 0, stream>>>(eidx, msbuf, (float4*)out_a2, E, N);

  grudec_kernel<<<(N+31)/32, 256, 0, stream>>>(A, hid, gruWi, grubi, gruWh, grubh, Tptr,
      decW1, decb1, decW2, decb2, x, pos, out_nf, out_final, N);
}